// Round 7
// baseline (661.976 us; speedup 1.0000x reference)
//
#include <hip/hip_runtime.h>
#include <cstdint>
#include <cstddef>
#include <math.h>

#define EMBED 1024
#define SEQ   2048
#define NROWS 4096   // B*S
#define NHEADS 16

typedef __bf16 bf16x8 __attribute__((ext_vector_type(8)));
typedef float f32x4 __attribute__((ext_vector_type(4)));
typedef unsigned short us8 __attribute__((ext_vector_type(8)));
typedef unsigned short us4 __attribute__((ext_vector_type(4)));

__device__ __forceinline__ unsigned short f2bf(float f) {
  union { float f; unsigned u; } v; v.f = f;
  unsigned r = v.u + 0x7fffu + ((v.u >> 16) & 1u);
  return (unsigned short)(r >> 16);
}
__device__ __forceinline__ float bf2f(unsigned short u) {
  union { unsigned u; float f; } v; v.u = (unsigned)u << 16; return v.f;
}

__device__ __forceinline__ bf16x8 as_bf(us8 u) { return __builtin_bit_cast(bf16x8, u); }

// ---------------------------------------------------------------------------
// All six weight transposes (fp32 [K][N] -> bf16 [N][K]) in ONE launch.
// ---------------------------------------------------------------------------
__global__ __launch_bounds__(256) void transpose_all(
    const float* __restrict__ Wq, const float* __restrict__ Wk,
    const float* __restrict__ Wv, const float* __restrict__ Wo,
    const float* __restrict__ W1, const float* __restrict__ W2,
    unsigned short* __restrict__ wqT, unsigned short* __restrict__ wkT,
    unsigned short* __restrict__ wvT, unsigned short* __restrict__ woT,
    unsigned short* __restrict__ w1T, unsigned short* __restrict__ w2T) {
  __shared__ float tile[32][33];
  const int bid = blockIdx.x;
  const float* in;
  unsigned short* out;
  int K, N, bx, by;
  if (bid < 4096) {
    const int w = bid >> 10, t = bid & 1023;
    in  = (w == 0) ? Wq  : (w == 1) ? Wk  : (w == 2) ? Wv  : Wo;
    out = (w == 0) ? wqT : (w == 1) ? wkT : (w == 2) ? wvT : woT;
    K = 1024; N = 1024; bx = t & 31; by = t >> 5;
  } else if (bid < 8192) {
    const int t = bid - 4096;
    in = W1; out = w1T; K = 1024; N = 4096; bx = t & 127; by = t >> 7;
  } else {
    const int t = bid - 8192;
    in = W2; out = w2T; K = 4096; N = 1024; bx = t & 31; by = t >> 5;
  }
  const int tx = threadIdx.x & 31, ty = threadIdx.x >> 5;  // 32 x 8
  const int n0 = bx * 32, k0 = by * 32;
#pragma unroll
  for (int i = 0; i < 4; i++) {
    int k = ty + i * 8;
    tile[k][tx] = in[(size_t)(k0 + k) * N + n0 + tx];
  }
  __syncthreads();
#pragma unroll
  for (int i = 0; i < 4; i++) {
    int n = ty + i * 8;
    out[(size_t)(n0 + n) * K + k0 + tx] = f2bf(tile[tx][n]);
  }
}

// ---------------------------------------------------------------------------
// LayerNorm: fp32 [rows][1024] -> bf16 [rows][1024].  One wave per row.
// ---------------------------------------------------------------------------
__global__ __launch_bounds__(256) void layernorm_bf16(
    const float* __restrict__ x, const float* __restrict__ g,
    const float* __restrict__ be, unsigned short* __restrict__ out) {
  const int wave = threadIdx.x >> 6, lane = threadIdx.x & 63;
  const int row = blockIdx.x * 4 + wave;
  const float* xr = x + (size_t)row * EMBED;
  float4 v[4];
  float s = 0.f, sq = 0.f;
#pragma unroll
  for (int c = 0; c < 4; c++) {
    v[c] = *(const float4*)&xr[c * 256 + lane * 4];
    s  += v[c].x + v[c].y + v[c].z + v[c].w;
    sq += v[c].x * v[c].x + v[c].y * v[c].y + v[c].z * v[c].z + v[c].w * v[c].w;
  }
#pragma unroll
  for (int m = 1; m < 64; m <<= 1) {
    s  += __shfl_xor(s, m, 64);
    sq += __shfl_xor(sq, m, 64);
  }
  const float mean = s * (1.f / 1024.f);
  const float var  = sq * (1.f / 1024.f) - mean * mean;
  const float rstd = rsqrtf(var + 1e-5f);
#pragma unroll
  for (int c = 0; c < 4; c++) {
    const int idx = c * 256 + lane * 4;
    us4 o;
    o[0] = f2bf((v[c].x - mean) * rstd * g[idx + 0] + be[idx + 0]);
    o[1] = f2bf((v[c].y - mean) * rstd * g[idx + 1] + be[idx + 1]);
    o[2] = f2bf((v[c].z - mean) * rstd * g[idx + 2] + be[idx + 2]);
    o[3] = f2bf((v[c].w - mean) * rstd * g[idx + 3] + be[idx + 3]);
    *(us4*)&out[(size_t)row * EMBED + idx] = o;
  }
}

// ---------------------------------------------------------------------------
// Fused LN2: h = x + pw0 + pw1 (WO split-K partials); writes h (fp32) and
// layernorm(h) (bf16).  One wave per row.
// ---------------------------------------------------------------------------
__global__ __launch_bounds__(256) void ln2_fused(
    const float* __restrict__ x,
    const unsigned short* __restrict__ pw0,
    const unsigned short* __restrict__ pw1,
    const float* __restrict__ g, const float* __restrict__ be,
    float* __restrict__ hb, unsigned short* __restrict__ out) {
  const int wave = threadIdx.x >> 6, lane = threadIdx.x & 63;
  const int row = blockIdx.x * 4 + wave;
  const size_t rb = (size_t)row * EMBED;
  float4 v[4];
  float s = 0.f, sq = 0.f;
#pragma unroll
  for (int c = 0; c < 4; c++) {
    const int idx = c * 256 + lane * 4;
    const float4 xv = *(const float4*)&x[rb + idx];
    const us4 a = *(const us4*)&pw0[rb + idx];
    const us4 d = *(const us4*)&pw1[rb + idx];
    v[c].x = xv.x + bf2f(a[0]) + bf2f(d[0]);
    v[c].y = xv.y + bf2f(a[1]) + bf2f(d[1]);
    v[c].z = xv.z + bf2f(a[2]) + bf2f(d[2]);
    v[c].w = xv.w + bf2f(a[3]) + bf2f(d[3]);
    *(float4*)&hb[rb + idx] = v[c];
    s  += v[c].x + v[c].y + v[c].z + v[c].w;
    sq += v[c].x * v[c].x + v[c].y * v[c].y + v[c].z * v[c].z + v[c].w * v[c].w;
  }
#pragma unroll
  for (int m = 1; m < 64; m <<= 1) {
    s  += __shfl_xor(s, m, 64);
    sq += __shfl_xor(sq, m, 64);
  }
  const float mean = s * (1.f / 1024.f);
  const float var  = sq * (1.f / 1024.f) - mean * mean;
  const float rstd = rsqrtf(var + 1e-5f);
#pragma unroll
  for (int c = 0; c < 4; c++) {
    const int idx = c * 256 + lane * 4;
    us4 o;
    o[0] = f2bf((v[c].x - mean) * rstd * g[idx + 0] + be[idx + 0]);
    o[1] = f2bf((v[c].y - mean) * rstd * g[idx + 1] + be[idx + 1]);
    o[2] = f2bf((v[c].z - mean) * rstd * g[idx + 2] + be[idx + 2]);
    o[3] = f2bf((v[c].w - mean) * rstd * g[idx + 3] + be[idx + 3]);
    *(us4*)&out[rb + idx] = o;
  }
}

// ---------------------------------------------------------------------------
// bf16 GEMM: C[M,N] = A[M,K] @ Bt[N,K]^T, 128x128 tile, BK=32.
// R7: NO LDS, NO barriers — operands loaded DIRECTLY from global in MFMA
// fragment layout (AITER-flatmm style).  A frag: row = wr+mi*16+l15, 16 B at
// col quad*8 (+k*32); B frag: row = wc+ni*16+l15 of Bt.  Lanes {i,i+16,i+32,
// i+48} cover one 64 B line -> 16 full lines per load, perfectly coalesced.
// Operands are L2/L3-resident for these sizes, so latency is cache-hit scale
// and hidden by parity-indexed 1-iter register prefetch + free inter-wave
// scheduling (no barriers).  Loop fully unrolled (NITER template) -> load
// offsets are immediates (k*64 B <= 1984 fits the 13-bit field).
// ---------------------------------------------------------------------------
enum { MODE_QKV = 0, MODE_WO = 1, MODE_FF1 = 2, MODE_FF2 = 3, MODE_PART = 4 };

template <int MODE, int NITER>
__global__ __launch_bounds__(256, 2) void gemm_bf16(
    const unsigned short* __restrict__ A,
    const unsigned short* __restrict__ Bt0,
    const unsigned short* __restrict__ Bt1,
    const unsigned short* __restrict__ Bt2,
    const float* __restrict__ bias0,
    const float* __restrict__ bias1,
    const float* __restrict__ bias2,
    const float* __restrict__ res,
    void* __restrict__ out0, void* __restrict__ out1,
    void* __restrict__ out2, void* __restrict__ out3,
    int M, int N, int K) {
  const unsigned short* Bt = Bt0;
  const float* bias = bias0;
  void* outv = out0;
  int zidx = 0;
  if constexpr (MODE == MODE_QKV) {
    zidx = blockIdx.z;
    if (zidx == 1)      { Bt = Bt1; bias = bias1; outv = out1; }
    else if (zidx == 2) { Bt = Bt2; bias = bias2; outv = out2; }
  }
  if constexpr (MODE == MODE_PART) {
    zidx = blockIdx.z;
    outv = (zidx == 0) ? out0 : (zidx == 1) ? out1 : (zidx == 2) ? out2 : out3;
  }
  const int koff = (MODE == MODE_PART) ? zidx * (NITER * 32) : 0;

  const int tid = threadIdx.x;
  const int wave = tid >> 6, lane = tid & 63;
  const int quad = lane >> 4, l15 = lane & 15;
  const int wr = (wave >> 1) * 64, wc = (wave & 1) * 64;
  const int rowA0 = blockIdx.y * 128, colB0 = blockIdx.x * 128;

  // per-lane fragment base pointers (loop-invariant; k advances via imm offset)
  const unsigned short* pA[4];
  const unsigned short* pB[4];
#pragma unroll
  for (int t = 0; t < 4; t++) {
    pA[t] = A  + (size_t)(rowA0 + wr + t * 16 + l15) * K + koff + quad * 8;
    pB[t] = Bt + (size_t)(colB0 + wc + t * 16 + l15) * K + koff + quad * 8;
  }

  f32x4 acc[4][4];
#pragma unroll
  for (int i = 0; i < 4; i++)
#pragma unroll
    for (int j = 0; j < 4; j++) acc[i][j] = f32x4{0.f, 0.f, 0.f, 0.f};

  // parity-indexed fragment sets: load k+1 while computing k (no v_movs —
  // indices are static under full unroll)
  us8 fa[2][4], fb[2][4];
#pragma unroll
  for (int t = 0; t < 4; t++) {
    fa[0][t] = *(const us8*)pA[t];
    fb[0][t] = *(const us8*)pB[t];
  }

#pragma unroll
  for (int k = 0; k < NITER; k++) {
    const int cur = k & 1;
    if (k + 1 < NITER) {
#pragma unroll
      for (int t = 0; t < 4; t++) {
        fa[cur ^ 1][t] = *(const us8*)(pA[t] + (k + 1) * 32);
        fb[cur ^ 1][t] = *(const us8*)(pB[t] + (k + 1) * 32);
      }
    }
#pragma unroll
    for (int mi = 0; mi < 4; mi++)
#pragma unroll
      for (int ni = 0; ni < 4; ni++)
        acc[mi][ni] = __builtin_amdgcn_mfma_f32_16x16x32_bf16(
            as_bf(fa[cur][mi]), as_bf(fb[cur][ni]), acc[mi][ni], 0, 0, 0);
  }

#pragma unroll
  for (int ni = 0; ni < 4; ni++) {
    const int col = colB0 + wc + ni * 16 + l15;
    float bv = 0.f;
    if constexpr (MODE == MODE_QKV || MODE == MODE_FF1 || MODE == MODE_FF2) bv = bias[col];
#pragma unroll
    for (int mi = 0; mi < 4; mi++) {
      const int row0 = rowA0 + wr + mi * 16 + quad * 4;  // 4 consecutive rows
      if constexpr (MODE == MODE_QKV) {
        unsigned short* o = (unsigned short*)outv;
        if (zidx == 2) {  // V: store transposed per head
          us4 pk;
#pragma unroll
          for (int r = 0; r < 4; r++) pk[r] = f2bf(acc[mi][ni][r] + bv);
          const int bb = row0 >> 11;     // batch (128-row tiles never straddle)
          const int sr = row0 & 2047;    // seq pos
          *(us4*)&o[((size_t)(bb * 1024 + col)) * SEQ + sr] = pk;
        } else {
#pragma unroll
          for (int r = 0; r < 4; r++)
            o[(size_t)(row0 + r) * N + col] = f2bf(acc[mi][ni][r] + bv);
        }
      } else if constexpr (MODE == MODE_FF1) {
        unsigned short* o = (unsigned short*)outv;
#pragma unroll
        for (int r = 0; r < 4; r++) {
          float v = acc[mi][ni][r] + bv;
          v = 0.5f * v * (1.f + erff(v * 0.7071067811865476f));
          o[(size_t)(row0 + r) * N + col] = f2bf(v);
        }
      } else if constexpr (MODE == MODE_PART) {
        unsigned short* o = (unsigned short*)outv;
#pragma unroll
        for (int r = 0; r < 4; r++)
          o[(size_t)(row0 + r) * N + col] = f2bf(acc[mi][ni][r]);
      } else {  // MODE_WO / MODE_FF2 : fp32 out with residual
        float* o = (float*)outv;
#pragma unroll
        for (int r = 0; r < 4; r++) {
          float v = acc[mi][ni][r] + bv + res[(size_t)(row0 + r) * N + col];
          o[(size_t)(row0 + r) * N + col] = v;
        }
      }
    }
  }
}

// ---------------------------------------------------------------------------
// FF2 split-K reduce: out = hb + b2[col] + sum of 4 bf16 partials.
// ---------------------------------------------------------------------------
__global__ __launch_bounds__(256) void ff2_reduce(
    const float* __restrict__ hb, const float* __restrict__ b2,
    const unsigned short* __restrict__ p0, const unsigned short* __restrict__ p1,
    const unsigned short* __restrict__ p2, const unsigned short* __restrict__ p3,
    float* __restrict__ out) {
  const size_t i = ((size_t)blockIdx.x * 256 + threadIdx.x) * 4;
  const int col = (int)(i & (EMBED - 1));
  const float4 h = *(const float4*)&hb[i];
  const float4 bb = *(const float4*)&b2[col];
  const us4 a = *(const us4*)&p0[i];
  const us4 b = *(const us4*)&p1[i];
  const us4 c = *(const us4*)&p2[i];
  const us4 d = *(const us4*)&p3[i];
  float4 o;
  o.x = h.x + bb.x + bf2f(a[0]) + bf2f(b[0]) + bf2f(c[0]) + bf2f(d[0]);
  o.y = h.y + bb.y + bf2f(a[1]) + bf2f(b[1]) + bf2f(c[1]) + bf2f(d[1]);
  o.z = h.z + bb.z + bf2f(a[2]) + bf2f(b[2]) + bf2f(c[2]) + bf2f(d[2]);
  o.w = h.w + bb.w + bf2f(a[3]) + bf2f(b[3]) + bf2f(c[3]) + bf2f(d[3]);
  *(float4*)&out[i] = o;
}

// ---------------------------------------------------------------------------
// Causal flash attention, S^T orientation, balanced + conflict-free (R4).
// ---------------------------------------------------------------------------
__global__ __launch_bounds__(256) void attn_kernel(
    const unsigned short* __restrict__ Q,
    const unsigned short* __restrict__ Kb,
    const unsigned short* __restrict__ Vt,
    unsigned short* __restrict__ Z) {
  __shared__ unsigned short Ksh[64][72];   // [key][64 d + pad]
  __shared__ unsigned short Vsh[64][72];   // [d][64 key + pad]
  __shared__ unsigned short Pt[4][16][72]; // per wave: [q][64 key + pad]
  __shared__ float Ot[4][64][17];          // per wave: [d][16 q + pad]

  const int tid = threadIdx.x;
  const int wave = tid >> 6, lane = tid & 63;
  const int quad = lane >> 4, l15 = lane & 15;
  const int bh = blockIdx.x, b = bh >> 4, h = bh & 15;
  const float cscale = 1.4426950408889634f / 32.f;  // log2(e)/sqrt(EMBED)

  const int srow = tid >> 2;       // 0..63 staging row
  const int sc = (tid & 3) * 8;    // staging col offset (shorts)
  const unsigned short* Kbase = Kb + (size_t)(b * SEQ) * EMBED + h * 64;
  const unsigned short* Vbase = Vt + (size_t)(b * 1024 + h * 64) * SEQ;

#pragma unroll
  for (int ph = 0; ph < 2; ph++) {
    const int j = ph ? 31 - (int)blockIdx.y : (int)blockIdx.y;  // q-tile (64 rows)
    const int qc = j * 64 + wave * 16;                          // this wave's 16 rows

    bf16x8 qf[2];
#pragma unroll
    for (int kf = 0; kf < 2; kf++)
      qf[kf] = as_bf(*(const us8*)&Q[(size_t)(b * SEQ + qc + l15) * EMBED +
                                     h * 64 + kf * 32 + quad * 8]);

    f32x4 accO[4];
#pragma unroll
    for (int dt = 0; dt < 4; dt++) accO[dt] = f32x4{0.f, 0.f, 0.f, 0.f};
    float mrun = -INFINITY, lrun = 0.f;

    for (int kt = 0; kt <= j; kt++) {
      const int kbase = kt * 64;
      const unsigned short* kg = Kbase + (size_t)(kbase + srow) * EMBED + sc;
      const unsigned short* vg = Vbase + (size_t)srow * SEQ + kbase + sc;
      const us8 k0 = *(const us8*)kg;
      const us8 k1 = *(const us8*)(kg + 32);
      const us8 v0 = *(const us8*)vg;
      const us8 v1 = *(const us8*)(vg + 32);
      __syncthreads();
      *(us8*)&Ksh[srow][sc]      = k0;
      *(us8*)&Ksh[srow][32 + sc] = k1;
      *(us8*)&Vsh[srow][sc]      = v0;
      *(us8*)&Vsh[srow][32 + sc] = v1;
      __syncthreads();

      f32x4 sf[4];
#pragma unroll
      for (int nt = 0; nt < 4; nt++) {
        f32x4 z4 = f32x4{0.f, 0.f, 0.f, 0.f};
#pragma unroll
        for (int kf = 0; kf < 2; kf++) {
          const bf16x8 ka = as_bf(*(const us8*)&Ksh[nt * 16 + l15][kf * 32 + quad * 8]);
          z4 = __builtin_amdgcn_mfma_f32_16x16x32_bf16(ka, qf[kf], z4, 0, 0, 0);
        }
        sf[nt] = z4 * cscale;
      }
      if (kt == j) {
        const int q = qc + l15;
#pragma unroll
        for (int nt = 0; nt < 4; nt++) {
          const int key0 = kbase + nt * 16 + quad * 4;
#pragma unroll
          for (int r = 0; r < 4; r++)
            if (key0 + r > q) sf[nt][r] = -INFINITY;
        }
      }
      float mx = sf[0][0];
#pragma unroll
      for (int nt = 0; nt < 4; nt++)
#pragma unroll
        for (int r = 0; r < 4; r++) mx = fmaxf(mx, sf[nt][r]);
      mx = fmaxf(mx, __shfl_xor(mx, 16, 64));
      mx = fmaxf(mx, __shfl_xor(mx, 32, 64));
      const float mnew = fmaxf(mrun, mx);
      const float alpha = exp2f(mrun - mnew);
      mrun = mnew;
      float rs = 0.f;
#pragma unroll
      for (int nt = 0; nt < 4; nt++) {
        us4 pk;
#pragma unroll
        for (int r = 0; r < 4; r++) {
          const float p = exp2f(sf[nt][r] - mnew);
          rs += p;
          pk[r] = f2bf(p);
        }
        *(us4*)&Pt[wave][l15][nt * 16 + quad * 4] = pk;
      }
      rs += __shfl_xor(rs, 16, 64);
      rs += __shfl_xor(rs, 32, 64);
      lrun = lrun * alpha + rs;
#pragma unroll
      for (int dt = 0; dt < 4; dt++) accO[dt] = accO[dt] * alpha;
      bf16x8 pf[2];
#pragma unroll
      for (int kk = 0; kk < 2; kk++)
        pf[kk] = as_bf(*(const us8*)&Pt[wave][l15][kk * 32 + quad * 8]);
#pragma unroll
      for (int dt = 0; dt < 4; dt++)
#pragma unroll
        for (int kk = 0; kk < 2; kk++) {
          const bf16x8 va = as_bf(*(const us8*)&Vsh[dt * 16 + l15][kk * 32 + quad * 8]);
          accO[dt] = __builtin_amdgcn_mfma_f32_16x16x32_bf16(va, pf[kk], accO[dt], 0, 0, 0);
        }
    }

    const float inv = 1.f / lrun;
#pragma unroll
    for (int dt = 0; dt < 4; dt++)
#pragma unroll
      for (int r = 0; r < 4; r++)
        Ot[wave][dt * 16 + quad * 4 + r][l15] = accO[dt][r] * inv;
    const int lq = lane >> 2, dbase = (lane & 3) * 16;
    us8 o0, o1;
#pragma unroll
    for (int i = 0; i < 8; i++) o0[i] = f2bf(Ot[wave][dbase + i][lq]);
#pragma unroll
    for (int i = 0; i < 8; i++) o1[i] = f2bf(Ot[wave][dbase + 8 + i][lq]);
    unsigned short* zp = Z + (size_t)(b * SEQ + qc + lq) * EMBED + h * 64 + dbase;
    *(us8*)zp = o0;
    *(us8*)(zp + 8) = o1;
  }
}

// ---------------------------------------------------------------------------
extern "C" void kernel_launch(void* const* d_in, const int* in_sizes, int n_in,
                              void* d_out, int out_size, void* d_ws, size_t ws_size,
                              hipStream_t stream) {
  const float* x   = (const float*)d_in[0];
  const float* Wq  = (const float*)d_in[1];
  const float* bq  = (const float*)d_in[2];
  const float* Wk  = (const float*)d_in[3];
  const float* bk  = (const float*)d_in[4];
  const float* Wv  = (const float*)d_in[5];
  const float* bv  = (const float*)d_in[6];
  const float* Wo  = (const float*)d_in[7];
  const float* W1  = (const float*)d_in[8];
  const float* b1  = (const float*)d_in[9];
  const float* W2  = (const float*)d_in[10];
  const float* b2  = (const float*)d_in[11];
  const float* g1  = (const float*)d_in[12];
  const float* be1 = (const float*)d_in[13];
  const float* g2  = (const float*)d_in[14];
  const float* be2 = (const float*)d_in[15];
  float* out = (float*)d_out;

  // Workspace map (MB offsets, 88 MB total):
  //  0- 8: wqT/wkT/wvT/woT  -> p0 (FF2 partial)
  //  8-16: w1T              -> p1
  // 16-24: w2T (live until FF2)
  // 24-32: ln1 -> zb (attn out) -> ln2 -> p2
  // 32-48: qb(32-40) + kb2(40-48) -> hb (fp32, after attn)
  // 48-56: vT -> pw0 (WO partial) -> p3
  // 56-88: m1 (56-64 doubles as pw1 before FF1)
  char* ws = (char*)d_ws;
  const size_t MB = 1024 * 1024;
  unsigned short* wqT = (unsigned short*)(ws + 0 * MB);
  unsigned short* wkT = (unsigned short*)(ws + 2 * MB);
  unsigned short* wvT = (unsigned short*)(ws + 4 * MB);
  unsigned short* woT = (unsigned short*)(ws + 6 * MB);
  unsigned short* w1T = (unsigned short*)(ws + 8 * MB);
  unsigned short* w2T = (unsigned short*)(ws + 16 * MB);
  unsigned short* ln1 = (unsigned short*)(ws + 24 * MB);
  unsigned short* zb  = (unsigned short*)(ws + 24 * MB);
  unsigned short* ln2 = (unsigned short*)(ws + 24 * MB);
  unsigned short* p2  = (unsigned short*)(ws + 24 * MB);
  unsigned short* qb  = (unsigned short*)(ws + 32 * MB);
  unsigned short* kb2 = (unsigned short*)(ws + 40 * MB);
  float*          hb  = (float*)         (ws + 32 * MB);
  unsigned short* vT  = (unsigned short*)(ws + 48 * MB);
  unsigned short* pw0 = (unsigned short*)(ws + 48 * MB);
  unsigned short* p3  = (unsigned short*)(ws + 48 * MB);
  unsigned short* pw1 = (unsigned short*)(ws + 56 * MB);
  unsigned short* m1  = (unsigned short*)(ws + 56 * MB);
  unsigned short* p0  = (unsigned short*)(ws + 0 * MB);
  unsigned short* p1  = (unsigned short*)(ws + 8 * MB);
  (void)in_sizes; (void)n_in; (void)out_size; (void)ws_size;

  transpose_all<<<12288, 256, 0, stream>>>(Wq, Wk, Wv, Wo, W1, W2,
                                           wqT, wkT, wvT, woT, w1T, w2T);

  layernorm_bf16<<<NROWS / 4, 256, 0, stream>>>(x, g1, be1, ln1);

  gemm_bf16<MODE_QKV, 32><<<dim3(8, 32, 3), 256, 0, stream>>>(
      ln1, wqT, wkT, wvT, bq, bk, bv, nullptr, qb, kb2, vT, nullptr,
      NROWS, 1024, 1024);

  attn_kernel<<<dim3(32, 16), 256, 0, stream>>>(qb, kb2, vT, zb);

  // WO: split-K=2 (NITER=16), bf16 partials; residual + LN fused below.
  gemm_bf16<MODE_PART, 16><<<dim3(8, 32, 2), 256, 0, stream>>>(
      zb, woT, nullptr, nullptr, nullptr, nullptr, nullptr, nullptr,
      pw0, pw1, nullptr, nullptr, NROWS, 1024, 1024);

  ln2_fused<<<NROWS / 4, 256, 0, stream>>>(x, pw0, pw1, g2, be2, hb, ln2);

  gemm_bf16<MODE_FF1, 32><<<dim3(32, 32), 256, 0, stream>>>(
      ln2, w1T, nullptr, nullptr, b1, nullptr, nullptr, nullptr,
      m1, nullptr, nullptr, nullptr, NROWS, 4096, 1024);

  // FF2: split-K=4 (NITER=32), bf16 partials, then reduce.
  gemm_bf16<MODE_PART, 32><<<dim3(8, 32, 4), 256, 0, stream>>>(
      m1, w2T, nullptr, nullptr, nullptr, nullptr, nullptr, nullptr,
      p0, p1, p2, p3, NROWS, 1024, 4096);

  ff2_reduce<<<NROWS * EMBED / (256 * 4), 256, 0, stream>>>(
      hb, b2, p0, p1, p2, p3, out);
}

// Round 8
// 369.652 us; speedup vs baseline: 1.7908x; 1.7908x over previous
//
#include <hip/hip_runtime.h>
#include <cstdint>
#include <cstddef>
#include <math.h>

#define EMBED 1024
#define SEQ   2048
#define NROWS 4096   // B*S
#define NHEADS 16

typedef __bf16 bf16x8 __attribute__((ext_vector_type(8)));
typedef float f32x4 __attribute__((ext_vector_type(4)));
typedef unsigned short us8 __attribute__((ext_vector_type(8)));
typedef unsigned short us4 __attribute__((ext_vector_type(4)));

__device__ __forceinline__ unsigned short f2bf(float f) {
  union { float f; unsigned u; } v; v.f = f;
  unsigned r = v.u + 0x7fffu + ((v.u >> 16) & 1u);
  return (unsigned short)(r >> 16);
}
__device__ __forceinline__ float bf2f(unsigned short u) {
  union { unsigned u; float f; } v; v.u = (unsigned)u << 16; return v.f;
}

__device__ __forceinline__ bf16x8 as_bf(us8 u) { return __builtin_bit_cast(bf16x8, u); }

// ---------------------------------------------------------------------------
// Prep: all six weight transposes (fp32 [K][N] -> bf16 [N][K]) AND LN1 in
// ONE launch.  bid<12288: transpose segments; bid>=12288: LN1 rows.
// ---------------------------------------------------------------------------
__global__ __launch_bounds__(256) void prep_kernel(
    const float* __restrict__ Wq, const float* __restrict__ Wk,
    const float* __restrict__ Wv, const float* __restrict__ Wo,
    const float* __restrict__ W1, const float* __restrict__ W2,
    unsigned short* __restrict__ wqT, unsigned short* __restrict__ wkT,
    unsigned short* __restrict__ wvT, unsigned short* __restrict__ woT,
    unsigned short* __restrict__ w1T, unsigned short* __restrict__ w2T,
    const float* __restrict__ x, const float* __restrict__ g1,
    const float* __restrict__ be1, unsigned short* __restrict__ ln1) {
  __shared__ float tile[32][33];
  const int bid = blockIdx.x;
  if (bid < 12288) {
    const float* in;
    unsigned short* out;
    int K, N, bx, by;
    if (bid < 4096) {
      const int w = bid >> 10, t = bid & 1023;
      in  = (w == 0) ? Wq  : (w == 1) ? Wk  : (w == 2) ? Wv  : Wo;
      out = (w == 0) ? wqT : (w == 1) ? wkT : (w == 2) ? wvT : woT;
      K = 1024; N = 1024; bx = t & 31; by = t >> 5;
    } else if (bid < 8192) {
      const int t = bid - 4096;
      in = W1; out = w1T; K = 1024; N = 4096; bx = t & 127; by = t >> 7;
    } else {
      const int t = bid - 8192;
      in = W2; out = w2T; K = 4096; N = 1024; bx = t & 31; by = t >> 5;
    }
    const int tx = threadIdx.x & 31, ty = threadIdx.x >> 5;  // 32 x 8
    const int n0 = bx * 32, k0 = by * 32;
#pragma unroll
    for (int i = 0; i < 4; i++) {
      int k = ty + i * 8;
      tile[k][tx] = in[(size_t)(k0 + k) * N + n0 + tx];
    }
    __syncthreads();
#pragma unroll
    for (int i = 0; i < 4; i++) {
      int n = ty + i * 8;
      out[(size_t)(n0 + n) * K + k0 + tx] = f2bf(tile[tx][n]);
    }
  } else {
    // LN1: 4 rows per block, one wave per row
    const int wave = threadIdx.x >> 6, lane = threadIdx.x & 63;
    const int row = (bid - 12288) * 4 + wave;
    const float* xr = x + (size_t)row * EMBED;
    float4 v[4];
    float s = 0.f, sq = 0.f;
#pragma unroll
    for (int c = 0; c < 4; c++) {
      v[c] = *(const float4*)&xr[c * 256 + lane * 4];
      s  += v[c].x + v[c].y + v[c].z + v[c].w;
      sq += v[c].x * v[c].x + v[c].y * v[c].y + v[c].z * v[c].z + v[c].w * v[c].w;
    }
#pragma unroll
    for (int m = 1; m < 64; m <<= 1) {
      s  += __shfl_xor(s, m, 64);
      sq += __shfl_xor(sq, m, 64);
    }
    const float mean = s * (1.f / 1024.f);
    const float var  = sq * (1.f / 1024.f) - mean * mean;
    const float rstd = rsqrtf(var + 1e-5f);
#pragma unroll
    for (int c = 0; c < 4; c++) {
      const int idx = c * 256 + lane * 4;
      us4 o;
      o[0] = f2bf((v[c].x - mean) * rstd * g1[idx + 0] + be1[idx + 0]);
      o[1] = f2bf((v[c].y - mean) * rstd * g1[idx + 1] + be1[idx + 1]);
      o[2] = f2bf((v[c].z - mean) * rstd * g1[idx + 2] + be1[idx + 2]);
      o[3] = f2bf((v[c].w - mean) * rstd * g1[idx + 3] + be1[idx + 3]);
      *(us4*)&ln1[(size_t)row * EMBED + idx] = o;
    }
  }
}

// ---------------------------------------------------------------------------
// Fused LN2: h = x + pw0 + pw1 (WO split-K partials); writes h (fp32) and
// layernorm(h) (bf16).  One wave per row.
// ---------------------------------------------------------------------------
__global__ __launch_bounds__(256) void ln2_fused(
    const float* __restrict__ x,
    const unsigned short* __restrict__ pw0,
    const unsigned short* __restrict__ pw1,
    const float* __restrict__ g, const float* __restrict__ be,
    float* __restrict__ hb, unsigned short* __restrict__ out) {
  const int wave = threadIdx.x >> 6, lane = threadIdx.x & 63;
  const int row = blockIdx.x * 4 + wave;
  const size_t rb = (size_t)row * EMBED;
  float4 v[4];
  float s = 0.f, sq = 0.f;
#pragma unroll
  for (int c = 0; c < 4; c++) {
    const int idx = c * 256 + lane * 4;
    const float4 xv = *(const float4*)&x[rb + idx];
    const us4 a = *(const us4*)&pw0[rb + idx];
    const us4 d = *(const us4*)&pw1[rb + idx];
    v[c].x = xv.x + bf2f(a[0]) + bf2f(d[0]);
    v[c].y = xv.y + bf2f(a[1]) + bf2f(d[1]);
    v[c].z = xv.z + bf2f(a[2]) + bf2f(d[2]);
    v[c].w = xv.w + bf2f(a[3]) + bf2f(d[3]);
    *(float4*)&hb[rb + idx] = v[c];
    s  += v[c].x + v[c].y + v[c].z + v[c].w;
    sq += v[c].x * v[c].x + v[c].y * v[c].y + v[c].z * v[c].z + v[c].w * v[c].w;
  }
#pragma unroll
  for (int m = 1; m < 64; m <<= 1) {
    s  += __shfl_xor(s, m, 64);
    sq += __shfl_xor(sq, m, 64);
  }
  const float mean = s * (1.f / 1024.f);
  const float var  = sq * (1.f / 1024.f) - mean * mean;
  const float rstd = rsqrtf(var + 1e-5f);
#pragma unroll
  for (int c = 0; c < 4; c++) {
    const int idx = c * 256 + lane * 4;
    us4 o;
    o[0] = f2bf((v[c].x - mean) * rstd * g[idx + 0] + be[idx + 0]);
    o[1] = f2bf((v[c].y - mean) * rstd * g[idx + 1] + be[idx + 1]);
    o[2] = f2bf((v[c].z - mean) * rstd * g[idx + 2] + be[idx + 2]);
    o[3] = f2bf((v[c].w - mean) * rstd * g[idx + 3] + be[idx + 3]);
    *(us4*)&out[rb + idx] = o;
  }
}

// ---------------------------------------------------------------------------
// bf16 GEMM (R6 structure, reverted from R7): 128x128 tile, BK=32,
// double-buffered LDS + 3-slot register prefetch, one barrier per iter.
// ---------------------------------------------------------------------------
enum { MODE_QKV = 0, MODE_WO = 1, MODE_FF1 = 2, MODE_FF2 = 3, MODE_PART = 4 };

#define LDW 36  // padded LDS row width (shorts)

template <int MODE, int NITER>
__global__ __launch_bounds__(256) void gemm_bf16(
    const unsigned short* __restrict__ A,
    const unsigned short* __restrict__ Bt0,
    const unsigned short* __restrict__ Bt1,
    const unsigned short* __restrict__ Bt2,
    const float* __restrict__ bias0,
    const float* __restrict__ bias1,
    const float* __restrict__ bias2,
    const float* __restrict__ res,
    void* __restrict__ out0, void* __restrict__ out1,
    void* __restrict__ out2, void* __restrict__ out3,
    int M, int N, int K) {
  const unsigned short* Bt = Bt0;
  const float* bias = bias0;
  void* outv = out0;
  int zidx = 0;
  if constexpr (MODE == MODE_QKV) {
    zidx = blockIdx.z;
    if (zidx == 1)      { Bt = Bt1; bias = bias1; outv = out1; }
    else if (zidx == 2) { Bt = Bt2; bias = bias2; outv = out2; }
  }
  if constexpr (MODE == MODE_PART) {
    zidx = blockIdx.z;
    outv = (zidx == 0) ? out0 : (zidx == 1) ? out1 : (zidx == 2) ? out2 : out3;
  }
  const int koff = (MODE == MODE_PART) ? zidx * (NITER * 32) : 0;

  __shared__ unsigned short As[2][128 * LDW];
  __shared__ unsigned short Bs[2][128 * LDW];
  const int tid = threadIdx.x;
  const int wave = tid >> 6, lane = tid & 63;
  const int quad = lane >> 4, l15 = lane & 15;
  const int wr = (wave >> 1) * 64, wc = (wave & 1) * 64;
  const int rowA0 = blockIdx.y * 128, colB0 = blockIdx.x * 128;

  const int srow = tid >> 2;
  const int scol = (tid & 3) * 8;
  const unsigned short* gA = A  + (size_t)(rowA0 + srow) * K + koff + scol;
  const unsigned short* gB = Bt + (size_t)(colB0 + srow) * K + koff + scol;
  const size_t half = (size_t)64 * K;

  us8 pa0[3], pa1[3], pb0[3], pb1[3];
#pragma unroll
  for (int s = 0; s < 3; s++) {
    if (s < NITER) {
      pa0[s] = *(const us8*)(gA + s * 32);
      pa1[s] = *(const us8*)(gA + half + s * 32);
      pb0[s] = *(const us8*)(gB + s * 32);
      pb1[s] = *(const us8*)(gB + half + s * 32);
    }
  }
  *(us8*)&As[0][srow * LDW + scol]        = pa0[0];
  *(us8*)&As[0][(srow + 64) * LDW + scol] = pa1[0];
  *(us8*)&Bs[0][srow * LDW + scol]        = pb0[0];
  *(us8*)&Bs[0][(srow + 64) * LDW + scol] = pb1[0];
  __syncthreads();

  f32x4 acc[4][4];
#pragma unroll
  for (int i = 0; i < 4; i++)
#pragma unroll
    for (int j = 0; j < 4; j++) acc[i][j] = f32x4{0.f, 0.f, 0.f, 0.f};

#pragma unroll
  for (int k = 0; k < NITER; k++) {
    const int buf = k & 1;
    if (k + 1 < NITER) {
      const int s = (k + 1) % 3;
      *(us8*)&As[buf ^ 1][srow * LDW + scol]        = pa0[s];
      *(us8*)&As[buf ^ 1][(srow + 64) * LDW + scol] = pa1[s];
      *(us8*)&Bs[buf ^ 1][srow * LDW + scol]        = pb0[s];
      *(us8*)&Bs[buf ^ 1][(srow + 64) * LDW + scol] = pb1[s];
    }
    if (k + 3 < NITER) {
      const int s = k % 3;
      pa0[s] = *(const us8*)(gA + (size_t)(k + 3) * 32);
      pa1[s] = *(const us8*)(gA + half + (size_t)(k + 3) * 32);
      pb0[s] = *(const us8*)(gB + (size_t)(k + 3) * 32);
      pb1[s] = *(const us8*)(gB + half + (size_t)(k + 3) * 32);
    }
    bf16x8 af[4], bfr[4];
#pragma unroll
    for (int mi = 0; mi < 4; mi++)
      af[mi] = as_bf(*(const us8*)&As[buf][(wr + mi * 16 + l15) * LDW + quad * 8]);
#pragma unroll
    for (int ni = 0; ni < 4; ni++)
      bfr[ni] = as_bf(*(const us8*)&Bs[buf][(wc + ni * 16 + l15) * LDW + quad * 8]);
#pragma unroll
    for (int mi = 0; mi < 4; mi++)
#pragma unroll
      for (int ni = 0; ni < 4; ni++)
        acc[mi][ni] = __builtin_amdgcn_mfma_f32_16x16x32_bf16(af[mi], bfr[ni], acc[mi][ni], 0, 0, 0);
    if (k + 1 < NITER) __syncthreads();
  }

#pragma unroll
  for (int ni = 0; ni < 4; ni++) {
    const int col = colB0 + wc + ni * 16 + l15;
    float bv = 0.f;
    if constexpr (MODE == MODE_QKV || MODE == MODE_FF1 || MODE == MODE_FF2) bv = bias[col];
#pragma unroll
    for (int mi = 0; mi < 4; mi++) {
      const int row0 = rowA0 + wr + mi * 16 + quad * 4;
      if constexpr (MODE == MODE_QKV) {
        unsigned short* o = (unsigned short*)outv;
        if (zidx == 2) {  // V: store transposed per head
          us4 pk;
#pragma unroll
          for (int r = 0; r < 4; r++) pk[r] = f2bf(acc[mi][ni][r] + bv);
          const int bb = row0 >> 11;
          const int sr = row0 & 2047;
          *(us4*)&o[((size_t)(bb * 1024 + col)) * SEQ + sr] = pk;
        } else {
#pragma unroll
          for (int r = 0; r < 4; r++)
            o[(size_t)(row0 + r) * N + col] = f2bf(acc[mi][ni][r] + bv);
        }
      } else if constexpr (MODE == MODE_PART) {
        unsigned short* o = (unsigned short*)outv;
#pragma unroll
        for (int r = 0; r < 4; r++)
          o[(size_t)(row0 + r) * N + col] = f2bf(acc[mi][ni][r]);
      } else {  // MODE_WO / MODE_FF2
        float* o = (float*)outv;
#pragma unroll
        for (int r = 0; r < 4; r++) {
          float v = acc[mi][ni][r] + bv + res[(size_t)(row0 + r) * N + col];
          o[(size_t)(row0 + r) * N + col] = v;
        }
      }
    }
  }
}

// ---------------------------------------------------------------------------
// gemm_big: 128(M) x 256(N) tile, BK=32 — 2x MFMA per staged byte vs 128².
// Wave owns 64x128 (32 MFMA/iter, 12 frag reads).  Double-buffered LDS
// (55 KB -> 2 blocks/CU, matches the 512-block grids), 2-slot parity
// prefetch (tile k+3 issued at iter k, consumed at k+2 -> 2-iter window).
// MODE in {MODE_FF1, MODE_PART}.
// ---------------------------------------------------------------------------
template <int MODE, int NITER>
__global__ __launch_bounds__(256, 2) void gemm_big(
    const unsigned short* __restrict__ A,
    const unsigned short* __restrict__ Bt,
    const float* __restrict__ bias,
    void* __restrict__ out0, void* __restrict__ out1,
    void* __restrict__ out2, void* __restrict__ out3,
    int M, int N, int K) {
  void* outv = out0;
  int zidx = 0;
  if constexpr (MODE == MODE_PART) {
    zidx = blockIdx.z;
    outv = (zidx == 0) ? out0 : (zidx == 1) ? out1 : (zidx == 2) ? out2 : out3;
  }
  const int koff = (MODE == MODE_PART) ? zidx * (NITER * 32) : 0;

  __shared__ unsigned short As[2][128 * LDW];
  __shared__ unsigned short Bs[2][256 * LDW];
  const int tid = threadIdx.x;
  const int wave = tid >> 6, lane = tid & 63;
  const int quad = lane >> 4, l15 = lane & 15;
  const int wr = (wave >> 1) * 64;    // M: 0 / 64
  const int wc = (wave & 1) * 128;    // N: 0 / 128
  const int rowA0 = blockIdx.y * 128, colB0 = blockIdx.x * 256;

  const int srow = tid >> 2;          // 0..63
  const int scol = (tid & 3) * 8;
  const unsigned short* gA = A  + (size_t)(rowA0 + srow) * K + koff + scol;
  const unsigned short* gB = Bt + (size_t)(colB0 + srow) * K + koff + scol;
  const size_t h64 = (size_t)64 * K;

  // 2 prefetch slots: slot s holds tile t with t&1==s.
  us8 pa[2][2], pb[2][4];
#pragma unroll
  for (int s = 0; s < 2; s++) {
    pa[s][0] = *(const us8*)(gA + s * 32);
    pa[s][1] = *(const us8*)(gA + h64 + s * 32);
#pragma unroll
    for (int j = 0; j < 4; j++)
      pb[s][j] = *(const us8*)(gB + (size_t)j * h64 + s * 32);
  }
  // stage tile 0 -> buf 0; refill slot 0 with tile 2
  *(us8*)&As[0][srow * LDW + scol]        = pa[0][0];
  *(us8*)&As[0][(srow + 64) * LDW + scol] = pa[0][1];
#pragma unroll
  for (int j = 0; j < 4; j++)
    *(us8*)&Bs[0][(srow + 64 * j) * LDW + scol] = pa[0][0][0] == pa[0][0][0] ? pb[0][j] : pb[0][j];
  if (2 < NITER) {
    pa[0][0] = *(const us8*)(gA + 2 * 32);
    pa[0][1] = *(const us8*)(gA + h64 + 2 * 32);
#pragma unroll
    for (int j = 0; j < 4; j++)
      pb[0][j] = *(const us8*)(gB + (size_t)j * h64 + 2 * 32);
  }
  __syncthreads();

  f32x4 acc[4][8];
#pragma unroll
  for (int i = 0; i < 4; i++)
#pragma unroll
    for (int j = 0; j < 8; j++) acc[i][j] = f32x4{0.f, 0.f, 0.f, 0.f};

#pragma unroll
  for (int k = 0; k < NITER; k++) {
    const int buf = k & 1;
    if (k + 1 < NITER) {
      const int s = (k + 1) & 1;
      *(us8*)&As[buf ^ 1][srow * LDW + scol]        = pa[s][0];
      *(us8*)&As[buf ^ 1][(srow + 64) * LDW + scol] = pa[s][1];
#pragma unroll
      for (int j = 0; j < 4; j++)
        *(us8*)&Bs[buf ^ 1][(srow + 64 * j) * LDW + scol] = pb[s][j];
      if (k + 3 < NITER) {
        pa[s][0] = *(const us8*)(gA + (size_t)(k + 3) * 32);
        pa[s][1] = *(const us8*)(gA + h64 + (size_t)(k + 3) * 32);
#pragma unroll
        for (int j = 0; j < 4; j++)
          pb[s][j] = *(const us8*)(gB + (size_t)j * h64 + (size_t)(k + 3) * 32);
      }
    }
    bf16x8 af[4];
#pragma unroll
    for (int mi = 0; mi < 4; mi++)
      af[mi] = as_bf(*(const us8*)&As[buf][(wr + mi * 16 + l15) * LDW + quad * 8]);
#pragma unroll
    for (int ni = 0; ni < 8; ni++) {
      const bf16x8 bfr = as_bf(*(const us8*)&Bs[buf][(wc + ni * 16 + l15) * LDW + quad * 8]);
#pragma unroll
      for (int mi = 0; mi < 4; mi++)
        acc[mi][ni] = __builtin_amdgcn_mfma_f32_16x16x32_bf16(af[mi], bfr, acc[mi][ni], 0, 0, 0);
    }
    if (k + 1 < NITER) __syncthreads();
  }

#pragma unroll
  for (int ni = 0; ni < 8; ni++) {
    const int col = colB0 + wc + ni * 16 + l15;
    float bv = 0.f;
    if constexpr (MODE == MODE_FF1) bv = bias[col];
#pragma unroll
    for (int mi = 0; mi < 4; mi++) {
      const int row0 = rowA0 + wr + mi * 16 + quad * 4;
      if constexpr (MODE == MODE_FF1) {
        unsigned short* o = (unsigned short*)outv;
#pragma unroll
        for (int r = 0; r < 4; r++) {
          float v = acc[mi][ni][r] + bv;
          v = 0.5f * v * (1.f + erff(v * 0.7071067811865476f));
          o[(size_t)(row0 + r) * N + col] = f2bf(v);
        }
      } else {  // MODE_PART
        unsigned short* o = (unsigned short*)outv;
#pragma unroll
        for (int r = 0; r < 4; r++)
          o[(size_t)(row0 + r) * N + col] = f2bf(acc[mi][ni][r]);
      }
    }
  }
}

// ---------------------------------------------------------------------------
// FF2 split-K reduce: out = hb + b2[col] + sum of 4 bf16 partials.
// ---------------------------------------------------------------------------
__global__ __launch_bounds__(256) void ff2_reduce(
    const float* __restrict__ hb, const float* __restrict__ b2,
    const unsigned short* __restrict__ p0, const unsigned short* __restrict__ p1,
    const unsigned short* __restrict__ p2, const unsigned short* __restrict__ p3,
    float* __restrict__ out) {
  const size_t i = ((size_t)blockIdx.x * 256 + threadIdx.x) * 4;
  const int col = (int)(i & (EMBED - 1));
  const float4 h = *(const float4*)&hb[i];
  const float4 bb = *(const float4*)&b2[col];
  const us4 a = *(const us4*)&p0[i];
  const us4 b = *(const us4*)&p1[i];
  const us4 c = *(const us4*)&p2[i];
  const us4 d = *(const us4*)&p3[i];
  float4 o;
  o.x = h.x + bb.x + bf2f(a[0]) + bf2f(b[0]) + bf2f(c[0]) + bf2f(d[0]);
  o.y = h.y + bb.y + bf2f(a[1]) + bf2f(b[1]) + bf2f(c[1]) + bf2f(d[1]);
  o.z = h.z + bb.z + bf2f(a[2]) + bf2f(b[2]) + bf2f(c[2]) + bf2f(d[2]);
  o.w = h.w + bb.w + bf2f(a[3]) + bf2f(b[3]) + bf2f(c[3]) + bf2f(d[3]);
  *(float4*)&out[i] = o;
}

// ---------------------------------------------------------------------------
// Causal flash attention, S^T orientation, balanced + conflict-free (R4).
// ---------------------------------------------------------------------------
__global__ __launch_bounds__(256) void attn_kernel(
    const unsigned short* __restrict__ Q,
    const unsigned short* __restrict__ Kb,
    const unsigned short* __restrict__ Vt,
    unsigned short* __restrict__ Z) {
  __shared__ unsigned short Ksh[64][72];
  __shared__ unsigned short Vsh[64][72];
  __shared__ unsigned short Pt[4][16][72];
  __shared__ float Ot[4][64][17];

  const int tid = threadIdx.x;
  const int wave = tid >> 6, lane = tid & 63;
  const int quad = lane >> 4, l15 = lane & 15;
  const int bh = blockIdx.x, b = bh >> 4, h = bh & 15;
  const float cscale = 1.4426950408889634f / 32.f;

  const int srow = tid >> 2;
  const int sc = (tid & 3) * 8;
  const unsigned short* Kbase = Kb + (size_t)(b * SEQ) * EMBED + h * 64;
  const unsigned short* Vbase = Vt + (size_t)(b * 1024 + h * 64) * SEQ;

#pragma unroll
  for (int ph = 0; ph < 2; ph++) {
    const int j = ph ? 31 - (int)blockIdx.y : (int)blockIdx.y;
    const int qc = j * 64 + wave * 16;

    bf16x8 qf[2];
#pragma unroll
    for (int kf = 0; kf < 2; kf++)
      qf[kf] = as_bf(*(const us8*)&Q[(size_t)(b * SEQ + qc + l15) * EMBED +
                                     h * 64 + kf * 32 + quad * 8]);

    f32x4 accO[4];
#pragma unroll
    for (int dt = 0; dt < 4; dt++) accO[dt] = f32x4{0.f, 0.f, 0.f, 0.f};
    float mrun = -INFINITY, lrun = 0.f;

    for (int kt = 0; kt <= j; kt++) {
      const int kbase = kt * 64;
      const unsigned short* kg = Kbase + (size_t)(kbase + srow) * EMBED + sc;
      const unsigned short* vg = Vbase + (size_t)srow * SEQ + kbase + sc;
      const us8 k0 = *(const us8*)kg;
      const us8 k1 = *(const us8*)(kg + 32);
      const us8 v0 = *(const us8*)vg;
      const us8 v1 = *(const us8*)(vg + 32);
      __syncthreads();
      *(us8*)&Ksh[srow][sc]      = k0;
      *(us8*)&Ksh[srow][32 + sc] = k1;
      *(us8*)&Vsh[srow][sc]      = v0;
      *(us8*)&Vsh[srow][32 + sc] = v1;
      __syncthreads();

      f32x4 sf[4];
#pragma unroll
      for (int nt = 0; nt < 4; nt++) {
        f32x4 z4 = f32x4{0.f, 0.f, 0.f, 0.f};
#pragma unroll
        for (int kf = 0; kf < 2; kf++) {
          const bf16x8 ka = as_bf(*(const us8*)&Ksh[nt * 16 + l15][kf * 32 + quad * 8]);
          z4 = __builtin_amdgcn_mfma_f32_16x16x32_bf16(ka, qf[kf], z4, 0, 0, 0);
        }
        sf[nt] = z4 * cscale;
      }
      if (kt == j) {
        const int q = qc + l15;
#pragma unroll
        for (int nt = 0; nt < 4; nt++) {
          const int key0 = kbase + nt * 16 + quad * 4;
#pragma unroll
          for (int r = 0; r < 4; r++)
            if (key0 + r > q) sf[nt][r] = -INFINITY;
        }
      }
      float mx = sf[0][0];
#pragma unroll
      for (int nt = 0; nt < 4; nt++)
#pragma unroll
        for (int r = 0; r < 4; r++) mx = fmaxf(mx, sf[nt][r]);
      mx = fmaxf(mx, __shfl_xor(mx, 16, 64));
      mx = fmaxf(mx, __shfl_xor(mx, 32, 64));
      const float mnew = fmaxf(mrun, mx);
      const float alpha = exp2f(mrun - mnew);
      mrun = mnew;
      float rs = 0.f;
#pragma unroll
      for (int nt = 0; nt < 4; nt++) {
        us4 pk;
#pragma unroll
        for (int r = 0; r < 4; r++) {
          const float p = exp2f(sf[nt][r] - mnew);
          rs += p;
          pk[r] = f2bf(p);
        }
        *(us4*)&Pt[wave][l15][nt * 16 + quad * 4] = pk;
      }
      rs += __shfl_xor(rs, 16, 64);
      rs += __shfl_xor(rs, 32, 64);
      lrun = lrun * alpha + rs;
#pragma unroll
      for (int dt = 0; dt < 4; dt++) accO[dt] = accO[dt] * alpha;
      bf16x8 pf[2];
#pragma unroll
      for (int kk = 0; kk < 2; kk++)
        pf[kk] = as_bf(*(const us8*)&Pt[wave][l15][kk * 32 + quad * 8]);
#pragma unroll
      for (int dt = 0; dt < 4; dt++)
#pragma unroll
        for (int kk = 0; kk < 2; kk++) {
          const bf16x8 va = as_bf(*(const us8*)&Vsh[dt * 16 + l15][kk * 32 + quad * 8]);
          accO[dt] = __builtin_amdgcn_mfma_f32_16x16x32_bf16(va, pf[kk], accO[dt], 0, 0, 0);
        }
    }

    const float inv = 1.f / lrun;
#pragma unroll
    for (int dt = 0; dt < 4; dt++)
#pragma unroll
      for (int r = 0; r < 4; r++)
        Ot[wave][dt * 16 + quad * 4 + r][l15] = accO[dt][r] * inv;
    const int lq = lane >> 2, dbase = (lane & 3) * 16;
    us8 o0, o1;
#pragma unroll
    for (int i = 0; i < 8; i++) o0[i] = f2bf(Ot[wave][dbase + i][lq]);
#pragma unroll
    for (int i = 0; i < 8; i++) o1[i] = f2bf(Ot[wave][dbase + 8 + i][lq]);
    unsigned short* zp = Z + (size_t)(b * SEQ + qc + lq) * EMBED + h * 64 + dbase;
    *(us8*)zp = o0;
    *(us8*)(zp + 8) = o1;
  }
}

// ---------------------------------------------------------------------------
extern "C" void kernel_launch(void* const* d_in, const int* in_sizes, int n_in,
                              void* d_out, int out_size, void* d_ws, size_t ws_size,
                              hipStream_t stream) {
  const float* x   = (const float*)d_in[0];
  const float* Wq  = (const float*)d_in[1];
  const float* bq  = (const float*)d_in[2];
  const float* Wk  = (const float*)d_in[3];
  const float* bk  = (const float*)d_in[4];
  const float* Wv  = (const float*)d_in[5];
  const float* bv  = (const float*)d_in[6];
  const float* Wo  = (const float*)d_in[7];
  const float* W1  = (const float*)d_in[8];
  const float* b1  = (const float*)d_in[9];
  const float* W2  = (const float*)d_in[10];
  const float* b2  = (const float*)d_in[11];
  const float* g1  = (const float*)d_in[12];
  const float* be1 = (const float*)d_in[13];
  const float* g2  = (const float*)d_in[14];
  const float* be2 = (const float*)d_in[15];
  float* out = (float*)d_out;

  // Workspace map (MB offsets, 88 MB total) — same as R5/R6.
  char* ws = (char*)d_ws;
  const size_t MB = 1024 * 1024;
  unsigned short* wqT = (unsigned short*)(ws + 0 * MB);
  unsigned short* wkT = (unsigned short*)(ws + 2 * MB);
  unsigned short* wvT = (unsigned short*)(ws + 4 * MB);
  unsigned short* woT = (unsigned short*)(ws + 6 * MB);
  unsigned short* w1T = (unsigned short*)(ws + 8 * MB);
  unsigned short* w2T = (unsigned short*)(ws + 16 * MB);
  unsigned short* ln1 = (unsigned short*)(ws + 24 * MB);
  unsigned short* zb  = (unsigned short*)(ws + 24 * MB);
  unsigned short* ln2 = (unsigned short*)(ws + 24 * MB);
  unsigned short* p2  = (unsigned short*)(ws + 24 * MB);
  unsigned short* qb  = (unsigned short*)(ws + 32 * MB);
  unsigned short* kb2 = (unsigned short*)(ws + 40 * MB);
  float*          hb  = (float*)         (ws + 32 * MB);
  unsigned short* vT  = (unsigned short*)(ws + 48 * MB);
  unsigned short* pw0 = (unsigned short*)(ws + 48 * MB);
  unsigned short* p3  = (unsigned short*)(ws + 48 * MB);
  unsigned short* pw1 = (unsigned short*)(ws + 56 * MB);
  unsigned short* m1  = (unsigned short*)(ws + 56 * MB);
  unsigned short* p0  = (unsigned short*)(ws + 0 * MB);
  unsigned short* p1  = (unsigned short*)(ws + 8 * MB);
  (void)in_sizes; (void)n_in; (void)out_size; (void)ws_size;

  // transposes + LN1 fused into one launch
  prep_kernel<<<12288 + NROWS / 4, 256, 0, stream>>>(
      Wq, Wk, Wv, Wo, W1, W2, wqT, wkT, wvT, woT, w1T, w2T, x, g1, be1, ln1);

  gemm_bf16<MODE_QKV, 32><<<dim3(8, 32, 3), 256, 0, stream>>>(
      ln1, wqT, wkT, wvT, bq, bk, bv, nullptr, qb, kb2, vT, nullptr,
      NROWS, 1024, 1024);

  attn_kernel<<<dim3(32, 16), 256, 0, stream>>>(qb, kb2, vT, zb);

  // WO: split-K=2 (NITER=16), bf16 partials; residual + LN fused below.
  gemm_bf16<MODE_PART, 16><<<dim3(8, 32, 2), 256, 0, stream>>>(
      zb, woT, nullptr, nullptr, nullptr, nullptr, nullptr, nullptr,
      pw0, pw1, nullptr, nullptr, NROWS, 1024, 1024);

  ln2_fused<<<NROWS / 4, 256, 0, stream>>>(x, pw0, pw1, g2, be2, hb, ln2);

  // FF1: 128x256 tile (512 blocks = 2/CU)
  gemm_big<MODE_FF1, 32><<<dim3(16, 32), 256, 0, stream>>>(
      ln2, w1T, b1, m1, nullptr, nullptr, nullptr, NROWS, 4096, 1024);

  // FF2: split-K=4, 128x256 tile (512 blocks), bf16 partials, then reduce.
  gemm_big<MODE_PART, 32><<<dim3(4, 32, 4), 256, 0, stream>>>(
      m1, w2T, nullptr, p0, p1, p2, p3, NROWS, 1024, 4096);

  ff2_reduce<<<NROWS * EMBED / (256 * 4), 256, 0, stream>>>(
      hb, b2, p0, p1, p2, p3, out);
}